// Round 1
// baseline (88.712 us; speedup 1.0000x reference)
//
#include <hip/hip_runtime.h>
#include <math.h>

#define GH 5
#define GW 10
#define HW 50            // GH*GW
#define NCLS 80
#define CPA 85           // channels per anchor (5 + 80)
#define NCH 255          // 3 * 85
#define SLICE 12750      // NCH * HW
#define NT 8             // targets per batch
#define IOU_THR 0.3f

__device__ __forceinline__ float softplusf(float x) {
    // log(1 + e^x), stable
    return fmaxf(x, 0.0f) + log1pf(expf(-fabsf(x)));
}
__device__ __forceinline__ float sigmoidf(float x) {
    return 1.0f / (1.0f + expf(-x));
}

__global__ __launch_bounds__(256) void yolo_main(
    const float* __restrict__ preds,
    const float* __restrict__ targets,
    const float* __restrict__ anchors,
    float* __restrict__ acc)   // acc[0]=coord_raw acc[1]=obj acc[2]=noobj_raw acc[3]=cls_raw
{
    __shared__ float ptile[NT][88];   // gathered 85 channels per target (pad to 88)
    __shared__ float stgt[NT][4];
    __shared__ int   slo[NT];         // first global-channel of best anchor (or sentinel)
    __shared__ int   syx[NT];         // cell index gy*GW+gx (or -1)
    __shared__ int   scls[NT];
    __shared__ int   svalid[NT];
    __shared__ float Ssh;
    __shared__ float wsum[4];
    __shared__ float accS[4];

    const int b   = blockIdx.x;
    const int tid = threadIdx.x;

    if (tid < 4) accS[tid] = 0.0f;

    // ---- per-target metadata (threads 0..7) ----
    if (tid < NT) {
        const float* tg = targets + ((size_t)b * NT + tid) * 5;
        float cls = tg[0], tx = tg[1], ty = tg[2], tw = tg[3], th = tg[4];
        int gx = (int)floorf(tx * (float)GW);
        int gy = (int)floorf(ty * (float)GH);
        float best_iou = -1.0f; int best_a = 0;
        #pragma unroll
        for (int a = 0; a < 3; ++a) {
            float aw = anchors[2*a], ah = anchors[2*a+1];
            float inter = fminf(tw, aw) * fminf(th, ah);
            float uni   = tw*th + aw*ah - inter;
            float iou   = inter / (uni + 1e-6f);
            if (iou > best_iou) { best_iou = iou; best_a = a; }  // first-max wins
        }
        int valid = (gx < GW) && (gy < GH) && (best_iou >= IOU_THR);
        int gxc = min(max(gx, 0), GW-1);
        int gyc = min(max(gy, 0), GH-1);
        float aw_s = anchors[2*best_a], ah_s = anchors[2*best_a+1];
        stgt[tid][0] = tx * (float)GW - (float)gx;
        stgt[tid][1] = ty * (float)GH - (float)gy;
        stgt[tid][2] = logf(tw / aw_s + 1e-6f);
        stgt[tid][3] = logf(th / ah_s + 1e-6f);
        scls[tid]   = (int)cls;
        svalid[tid] = valid;
        slo[tid]    = valid ? best_a * CPA : (1 << 28);
        syx[tid]    = valid ? gyc * GW + gxc : -1;
    }
    __syncthreads();

    // copy match keys to registers (avoid LDS reads in hot loop)
    int rlo[NT], ryx[NT];
    #pragma unroll
    for (int t = 0; t < NT; ++t) { rlo[t] = slo[t]; ryx[t] = syx[t]; }

    // ---- stream the batch slice once (coalesced float2), scatter matches ----
    const float2* src = reinterpret_cast<const float2*>(preds + (size_t)b * SLICE);
    float s_local = 0.0f;
    for (int f = tid; f < SLICE/2; f += 256) {
        float2 v = src[f];
        int e0  = f << 1;
        int ci  = e0 / HW;          // global channel 0..254 (float2 never crosses a channel)
        int yx0 = e0 - ci * HW;     // even
        if (ci == 4 || ci == 89 || ci == 174) {   // obj channel of anchors 0/1/2
            s_local += softplusf(sigmoidf(v.x)) + softplusf(sigmoidf(v.y));
        }
        #pragma unroll
        for (int t = 0; t < NT; ++t) {
            unsigned cc = (unsigned)(ci - rlo[t]);
            if (cc < (unsigned)CPA) {
                if (yx0     == ryx[t]) ptile[t][cc] = v.x;
                if (yx0 + 1 == ryx[t]) ptile[t][cc] = v.y;
            }
        }
    }

    // ---- reduce S[b] = sum softplus(sigmoid(obj)) over all 150 cells ----
    #pragma unroll
    for (int off = 32; off > 0; off >>= 1) s_local += __shfl_xor(s_local, off);
    const int wid = tid >> 6, lane = tid & 63;
    if (lane == 0) wsum[wid] = s_local;
    __syncthreads();
    if (tid == 0) Ssh = wsum[0] + wsum[1] + wsum[2] + wsum[3];
    __syncthreads();
    const float S = Ssh;

    // ---- per-target losses: one wave per target (4 waves x 2 rounds) ----
    for (int t = wid; t < NT; t += 4) {
        if (!svalid[t]) continue;
        float v0 = ptile[t][lane];                              // channels 0..63
        float v1 = (lane < CPA - 64) ? ptile[t][64 + lane] : 0.0f; // channels 64..84
        // logsumexp over class logits (channels 5..84)
        float m = -INFINITY;
        if (lane >= 5)        m = v0;
        if (lane < CPA - 64)  m = fmaxf(m, v1);
        #pragma unroll
        for (int off = 32; off > 0; off >>= 1) m = fmaxf(m, __shfl_xor(m, off));
        float s = 0.0f, csq = 0.0f;
        if (lane >= 5)        s += expf(v0 - m);
        if (lane < CPA - 64)  s += expf(v1 - m);
        if (lane < 4) { float d = v0 - stgt[t][lane]; csq = d * d; }
        #pragma unroll
        for (int off = 32; off > 0; off >>= 1) {
            s   += __shfl_xor(s, off);
            csq += __shfl_xor(csq, off);
        }
        float p4 = __shfl(v0, 4);
        int cch = 5 + scls[t];
        float pl = (cch < 64) ? __shfl(v0, cch) : __shfl(v1, cch - 64);
        float ce = m + logf(s) - pl;
        float z    = sigmoidf(p4);
        float spz  = softplusf(z);
        float spnz = softplusf(-z);
        if (lane == 0) {
            atomicAdd(&accS[0], csq);
            atomicAdd(&accS[1], spnz);
            atomicAdd(&accS[2], S - spz);
            atomicAdd(&accS[3], ce);
        }
    }
    __syncthreads();
    if (tid < 4) atomicAdd(&acc[tid], accS[tid]);
}

__global__ void yolo_final(const float* __restrict__ acc,
                           float* __restrict__ out, float denom) {
    if (threadIdx.x == 0 && blockIdx.x == 0) {
        float lc   = acc[0] / denom;        // loss_coord
        float lo   = acc[1];                // loss_obj
        float ln   = 0.5f * acc[2];         // loss_noobj = LAMBDA_NOOBJ * raw
        float lcls = acc[3] / denom;        // loss_cls
        float tot  = 5.0f * lc + lo + 0.5f * ln + lcls;
        out[0] = tot; out[1] = lc; out[2] = lo; out[3] = ln; out[4] = lcls;
    }
}

extern "C" void kernel_launch(void* const* d_in, const int* in_sizes, int n_in,
                              void* d_out, int out_size, void* d_ws, size_t ws_size,
                              hipStream_t stream) {
    const float* preds   = (const float*)d_in[0];
    const float* targets = (const float*)d_in[1];
    const float* anchors = (const float*)d_in[2];
    float* out = (float*)d_out;
    float* acc = (float*)d_ws;

    int B = in_sizes[0] / SLICE;   // 4096

    hipMemsetAsync(acc, 0, 4 * sizeof(float), stream);
    yolo_main<<<B, 256, 0, stream>>>(preds, targets, anchors, acc);
    yolo_final<<<1, 64, 0, stream>>>(acc, out, (float)B * (float)NT);
}